// Round 7
// baseline (11217.387 us; speedup 1.0000x reference)
//
#include <hip/hip_runtime.h>

typedef _Float16 h2_t  __attribute__((ext_vector_type(2)));
typedef _Float16 f16x8 __attribute__((ext_vector_type(8)));
typedef float    f32x4 __attribute__((ext_vector_type(4)));

#define HID  100
#define TENC 4096
#define TDEC 4096
#define NCLS 6
#define NTHR 512   // 8 waves, 2 per SIMD: TLP overlaps one wave's MFMA with the other's VALU/DS

__device__ __forceinline__ float sigm(float v)  { return __builtin_amdgcn_rcpf(1.0f + __expf(-v)); }
__device__ __forceinline__ float tanh_(float v) { return 1.0f - 2.0f * __builtin_amdgcn_rcpf(1.0f + __expf(2.0f * v)); }

// lgkm-only barrier: does NOT drain vmcnt, so global stores stay in flight
// across steps (unlike __syncthreads).
#define SYNC_LDS() asm volatile("s_waitcnt lgkmcnt(0)\n\ts_barrier" ::: "memory")

__device__ __forceinline__ float packh2(float a, float b) {
    h2_t p; p[0] = (_Float16)a; p[1] = (_Float16)b;
    return __builtin_bit_cast(float, p);
}

// Persistent single-workgroup LSTM, v11. Diff vs v10 (R12, 4178us PASSED):
// v10's counters: MfmaBusy ~397cy/step (matrix pipe saturated: 25 MFMA/SIMD
// x ~16cy), VGPR 144 < ~156 live -> SPILLS (FETCH +10MB), 1 wave/SIMD so
// MFMA/VALU/DS serialize in one wave. v11 keeps the EXACT same math/mapping
// (absmax was bit-identical to the fdot2 version) but:
//  - 512 threads / 8 waves: tiles per wave 7 -> 3..4, wA 112 -> <=64 VGPRs
//    (no spill), and 2 waves/SIMD overlap VALU with MFMA.
//  - persistent zero f32x4 for the MFMA C-input (D regs != C regs is legal):
//    kills 16 v_mov/step of accumulator zeroing.
//  - select tree over 4 tiles instead of 7.
__global__ __launch_bounds__(NTHR, 1)
void lstm_rec(const float* __restrict__ x,      // [TENC*3]
              const int*   __restrict__ y,      // [TDEC]
              const float* __restrict__ eWih,   // [400*3]
              const float* __restrict__ eWhh,   // [400*HID]
              const float* __restrict__ ebih,
              const float* __restrict__ ebhh,
              const float* __restrict__ dWih,   // [400]
              const float* __restrict__ dWhh,
              const float* __restrict__ dbih,
              const float* __restrict__ dbhh,
              float* __restrict__ hsto)         // [(TDEC-1)*HID] decoder h history
{
    __shared__ __align__(16) _Float16 hbuf[2][128];  // [parity][k-slot]: 0-99 h, 100-103 input, 104-127 zero
    __shared__ __align__(8)  uint2    xst[TENC];     // packed f16: {x0,x1},{x2,1}
    __shared__               unsigned yst[TDEC];     // packed f16: {yf,0}

    const int t   = threadIdx.x;
    const int w   = t >> 6;
    const int l   = t & 63;
    const int col = l & 15;     // A-row-in-tile / D-col (replica id)
    const int lg  = l >> 4;     // k-chunk id for A/B; cell-in-tile group for D
    const int nt   = (w == 0) ? 4 : 3;              // tiles this wave owns
    const int base = (w == 0) ? 0 : 4 + (w - 1) * 3; // 4 + 7*3 = 25 tiles total
    const int gate = col & 3;   // interleaved row order: R in tile -> (cell=R>>2, gate=R&3)

    // ---- stage x (f16 pairs) and y (f16) into LDS; zero h buffers ----
    for (int i = t; i < TENC; i += NTHR) {
        const float a = x[3*i], b = x[3*i+1], cc = x[3*i+2];
        uint2 u;
        u.x = __builtin_bit_cast(unsigned, packh2(a, b));
        u.y = __builtin_bit_cast(unsigned, packh2(cc, 1.0f));
        xst[i] = u;
    }
    for (int i = t; i < TDEC; i += NTHR)
        yst[i] = __builtin_bit_cast(unsigned, packh2((float)y[i], 0.0f));
    if (t < 256) ((_Float16*)hbuf)[t] = (_Float16)0.0f;   // both parities, all 128 slots
    __syncthreads();

    // x_0 into hbuf[0][100..103] (thread 0; published by the SYNC_LDS below)
    if (t == 0) {
        uint2 u;
        u.x = __builtin_bit_cast(unsigned, packh2(x[0], x[1]));
        u.y = __builtin_bit_cast(unsigned, packh2(x[2], 1.0f));
        *(uint2*)&hbuf[0][100] = u;
    }

    // ---- encoder A-fragments: wA[tile][ktile], lane holds W[R=16T+col][k=32kt+8lg+j] ----
    f16x8 wA[4][4];
    #pragma unroll
    for (int tt = 0; tt < 4; ++tt) {
        #pragma unroll
        for (int kt = 0; kt < 4; ++kt) {
            f16x8 a;
            #pragma unroll
            for (int j = 0; j < 8; ++j) {
                float v = 0.0f;
                if (tt < nt) {
                    const int cellA = 4*(base + tt) + (col >> 2);
                    const int wrow  = gate * HID + cellA;
                    const int k     = 32*kt + 8*lg + j;
                    if (k < HID)            v = eWhh[wrow*HID + k];
                    else if (k < HID + 3)   v = eWih[wrow*3 + (k - HID)];
                    else if (k == HID + 3)  v = ebih[wrow] + ebhh[wrow];
                }
                a[j] = (_Float16)v;
            }
            wA[tt][kt] = a;
        }
    }
    SYNC_LDS();

    // this lane's owned cell (replica fan-out): ts = col mod nt (outside loop)
    const int ts = col % nt;
    const int cell = 4*(base + ts) + lg;
    const bool s1 = (ts == 1), s2 = (ts == 2), s3 = (ts == 3);
    const bool wr4 = (col < nt);            // unique writer per cell

    const f32x4 ZZ = {0.0f, 0.0f, 0.0f, 0.0f};
    float c = 0.0f;
    int p = 0;

    // ================ encoder: 4096 steps ================
    for (int s = 0; s < TENC; ++s) {
        const f16x8* hb = (const f16x8*)hbuf[p];
        const f16x8 B0 = hb[ 0 + lg];     // k  0..31 chunk lg
        const f16x8 B1 = hb[ 4 + lg];     // k 32..63
        const f16x8 B2 = hb[ 8 + lg];     // k 64..95
        const f16x8 B3 = hb[12 + lg];     // k 96..127

        // prefetch x_{s+1} into the other parity's input slots
        if (t == 0 && s + 1 < TENC)
            *(uint2*)&hbuf[p ^ 1][100] = xst[s + 1];

        f32x4 acc[4];
        #pragma unroll
        for (int tt = 0; tt < 4; ++tt) {
            if (tt < nt) {
                f32x4 z = __builtin_amdgcn_mfma_f32_16x16x32_f16(wA[tt][0], B0, ZZ, 0, 0, 0);
                z = __builtin_amdgcn_mfma_f32_16x16x32_f16(wA[tt][1], B1, z, 0, 0, 0);
                z = __builtin_amdgcn_mfma_f32_16x16x32_f16(wA[tt][2], B2, z, 0, 0, 0);
                z = __builtin_amdgcn_mfma_f32_16x16x32_f16(wA[tt][3], B3, z, 0, 0, 0);
                acc[tt] = z;
            }
        }

        // static-index select of this lane's tile quad (rule #20: no runtime idx)
        f32x4 q = acc[0];
        if (s1) q = acc[1];
        if (s2) q = acc[2];
        if (s3) q = acc[3];

        const float fi = sigm(q[0]), ff = sigm(q[1]), fg = tanh_(q[2]), fo = sigm(q[3]);
        c = ff * c + fi * fg;
        const float hn = fo * tanh_(c);
        if (wr4)
            hbuf[p ^ 1][cell] = (_Float16)hn;
        SYNC_LDS();
        p ^= 1;
    }

    // ================ transition: decoder input slot {yf0, 1, 0, 0} ================
    if (t == 0) {
        uint2 v;
        v.x = (yst[0] & 0xFFFFu) | 0x3C000000u;   // {yf0, f16(1.0)}
        v.y = 0u;
        *(uint2*)&hbuf[p][100] = v;
    }

    // ---- decoder A-fragments (reuse wA) ----
    #pragma unroll
    for (int tt = 0; tt < 4; ++tt) {
        #pragma unroll
        for (int kt = 0; kt < 4; ++kt) {
            f16x8 a;
            #pragma unroll
            for (int j = 0; j < 8; ++j) {
                float v = 0.0f;
                if (tt < nt) {
                    const int cellA = 4*(base + tt) + (col >> 2);
                    const int wrow  = gate * HID + cellA;
                    const int k     = 32*kt + 8*lg + j;
                    if (k < HID)            v = dWhh[wrow*HID + k];
                    else if (k == HID)      v = dWih[wrow];
                    else if (k == HID + 1)  v = dbih[wrow] + dbhh[wrow];
                }
                a[j] = (_Float16)v;
            }
            wA[tt][kt] = a;
        }
    }
    SYNC_LDS();

    // ================ decoder: 4095 steps (ratio==1 -> teacher-forced) ================
    for (int s = 0; s < TDEC - 1; ++s) {
        const f16x8* hb = (const f16x8*)hbuf[p];
        const f16x8 B0 = hb[ 0 + lg];
        const f16x8 B1 = hb[ 4 + lg];
        const f16x8 B2 = hb[ 8 + lg];
        const f16x8 B3 = hb[12 + lg];

        if (t == 0 && s + 1 < TDEC - 1) {
            uint2 v;
            v.x = (yst[s + 1] & 0xFFFFu) | 0x3C000000u;
            v.y = 0u;
            *(uint2*)&hbuf[p ^ 1][100] = v;
        }

        f32x4 acc[4];
        #pragma unroll
        for (int tt = 0; tt < 4; ++tt) {
            if (tt < nt) {
                f32x4 z = __builtin_amdgcn_mfma_f32_16x16x32_f16(wA[tt][0], B0, ZZ, 0, 0, 0);
                z = __builtin_amdgcn_mfma_f32_16x16x32_f16(wA[tt][1], B1, z, 0, 0, 0);
                z = __builtin_amdgcn_mfma_f32_16x16x32_f16(wA[tt][2], B2, z, 0, 0, 0);
                z = __builtin_amdgcn_mfma_f32_16x16x32_f16(wA[tt][3], B3, z, 0, 0, 0);
                acc[tt] = z;
            }
        }

        f32x4 q = acc[0];
        if (s1) q = acc[1];
        if (s2) q = acc[2];
        if (s3) q = acc[3];

        const float fi = sigm(q[0]), ff = sigm(q[1]), fg = tanh_(q[2]), fo = sigm(q[3]);
        c = ff * c + fi * fg;
        const float hn = fo * tanh_(c);
        if (wr4) {
            hbuf[p ^ 1][cell] = (_Float16)hn;
            hsto[s * HID + cell] = hn;      // global store, never fenced in-loop
        }
        SYNC_LDS();
        p ^= 1;
    }
    // kernel end-of-dispatch drains the hsto stores before logits_k launches
}

// Parallel logits: out[t][r] = linW[r] . h_t + linb[r], last row zeroed.
__global__ __launch_bounds__(256)
void logits_k(const float* __restrict__ hsto, const float* __restrict__ linW,
              const float* __restrict__ linb, float* __restrict__ out)
{
    const int idx = blockIdx.x * 256 + threadIdx.x;
    if (idx >= TDEC * NCLS) return;
    const int tt = idx / NCLS;
    const int r  = idx % NCLS;
    if (tt >= TDEC - 1) { out[idx] = 0.0f; return; }
    const float* h  = hsto + tt * HID;
    const float* wr = linW + r * HID;
    float a = linb[r];
    #pragma unroll 4
    for (int k = 0; k < HID; ++k) a += wr[k] * h[k];
    out[idx] = a;
}

extern "C" void kernel_launch(void* const* d_in, const int* in_sizes, int n_in,
                              void* d_out, int out_size, void* d_ws, size_t ws_size,
                              hipStream_t stream)
{
    const float* x    = (const float*)d_in[0];
    const int*   y    = (const int*)  d_in[1];
    const float* eWih = (const float*)d_in[2];
    const float* eWhh = (const float*)d_in[3];
    const float* ebih = (const float*)d_in[4];
    const float* ebhh = (const float*)d_in[5];
    const float* dWih = (const float*)d_in[6];
    const float* dWhh = (const float*)d_in[7];
    const float* dbih = (const float*)d_in[8];
    const float* dbhh = (const float*)d_in[9];
    const float* linW = (const float*)d_in[10];
    const float* linb = (const float*)d_in[11];
    float* out  = (float*)d_out;
    float* hsto = (float*)d_ws;   // (TDEC-1)*HID*4 = 1.64 MB scratch

    lstm_rec<<<dim3(1), dim3(NTHR), 0, stream>>>(
        x, y, eWih, eWhh, ebih, ebhh, dWih, dWhh, dbih, dbhh, hsto);

    const int nout = TDEC * NCLS;
    logits_k<<<dim3((nout + 255) / 256), dim3(256), 0, stream>>>(hsto, linW, linb, out);
}

// Round 8
// 5179.777 us; speedup vs baseline: 2.1656x; 2.1656x over previous
//
#include <hip/hip_runtime.h>

typedef _Float16 h2_t  __attribute__((ext_vector_type(2)));
typedef _Float16 f16x8 __attribute__((ext_vector_type(8)));
typedef float    f32x4 __attribute__((ext_vector_type(4)));

#define HID  100
#define TENC 4096
#define TDEC 4096
#define NCLS 6
#define NTHR 512   // 8 waves, 2/SIMD; launch_bounds min-waves=2 pins VGPR budget to 256 (v11 post-mortem: heuristic gave 84 -> L2-scratch spills on the serial chain)

__device__ __forceinline__ float sigm(float v)  { return __builtin_amdgcn_rcpf(1.0f + __expf(-v)); }
__device__ __forceinline__ float tanh_(float v) { return 1.0f - 2.0f * __builtin_amdgcn_rcpf(1.0f + __expf(2.0f * v)); }

// lgkm-only barrier (proven v8-v11): does NOT drain vmcnt.
#define SYNC_LDS() asm volatile("s_waitcnt lgkmcnt(0)\n\ts_barrier" ::: "memory")

__device__ __forceinline__ float packh2(float a, float b) {
    h2_t p; p[0] = (_Float16)a; p[1] = (_Float16)b;
    return __builtin_bit_cast(float, p);
}

// fdot2 shorthand
__device__ __forceinline__ float fd2(float w, float h, float acc) {
    return __builtin_amdgcn_fdot2(__builtin_bit_cast(h2_t, w),
                                  __builtin_bit_cast(h2_t, h), acc, false);
}

// Sum over the 4 replica columns {c, c+4, c+8, c+12} (mod 16) via cyclic DPP
// rotations: row_ror:8 then row_ror:4. Rotation-closure makes the summed set
// {i, i+4, i+8, i+12} REGARDLESS of rotate direction convention — the same
// immunity argument as the proven xor-1 quad_perm (v8). Pure VALU.
__device__ __forceinline__ float rsum4(float v) {
    const int a = __builtin_amdgcn_update_dpp(
        0, __builtin_bit_cast(int, v), 0x128, 0xF, 0xF, true);   // row_ror:8
    float s = v + __builtin_bit_cast(float, a);
    const int b = __builtin_amdgcn_update_dpp(
        0, __builtin_bit_cast(int, s), 0x124, 0xF, 0xF, true);   // row_ror:4
    return s + __builtin_bit_cast(float, b);
}

// Persistent single-workgroup LSTM, v12 — HYBRID matrix+vector K-split.
// MFMA (verified v10/v11 mapping) handles k in [0,64): rows gate-interleaved
// R=16T+col, A-row=col, C/D: lane(col,lg) reg r = gate r of cell 4T+lg.
// VALU handles k in [64,104): replica column rep=col>>2 takes slice
// [64+10rep, 74+10rep) — x & bias live in k-slots 100..103 (rep3's slice).
// Replica partials summed with rsum4; gates = MFMA quad + VALU partial.
// 28 tiles (rows padded to 448) over 7 working waves x 4 tiles (uniform).
// Both pipes run concurrently (m114); 2 waves/SIMD overlap the rest.
__global__ __launch_bounds__(NTHR, 2)
void lstm_rec(const float* __restrict__ x,      // [TENC*3]
              const int*   __restrict__ y,      // [TDEC]
              const float* __restrict__ eWih,   // [400*3]
              const float* __restrict__ eWhh,   // [400*HID]
              const float* __restrict__ ebih,
              const float* __restrict__ ebhh,
              const float* __restrict__ dWih,   // [400]
              const float* __restrict__ dWhh,
              const float* __restrict__ dbih,
              const float* __restrict__ dbhh,
              float* __restrict__ hsto)         // [(TDEC-1)*HID] decoder h history
{
    __shared__ __align__(16) _Float16 hbuf[2][128];  // [parity][k-slot]: 0-99 h, 100-103 input, 104-127 zero
    __shared__ __align__(8)  uint2    xst[TENC];     // packed f16: {x0,x1},{x2,1}
    __shared__               unsigned yst[TDEC];     // packed f16: {yf,0}

    const int t   = threadIdx.x;
    const int w   = t >> 6;
    const int l   = t & 63;
    const int col = l & 15;     // A-row-in-tile / D-col
    const int lg  = l >> 4;     // k-chunk id (A/B); cell-in-tile group (D)
    const int T   = col & 3;    // owned tile slot (nt=4 uniform) AND A-row gate
    const int rep = col >> 2;   // replica id: A cellA offset, VALU k-slice, writer
    const bool alive = (w < 7); // 7 working waves x 4 tiles = 28 tiles (25 live)

    // ---- stage x (f16 pairs) and y (f16) into LDS; zero h buffers ----
    for (int i = t; i < TENC; i += NTHR) {
        const float a = x[3*i], b = x[3*i+1], cc = x[3*i+2];
        uint2 u;
        u.x = __builtin_bit_cast(unsigned, packh2(a, b));
        u.y = __builtin_bit_cast(unsigned, packh2(cc, 1.0f));
        xst[i] = u;
    }
    for (int i = t; i < TDEC; i += NTHR)
        yst[i] = __builtin_bit_cast(unsigned, packh2((float)y[i], 0.0f));
    if (t < 256) ((_Float16*)hbuf)[t] = (_Float16)0.0f;   // both parities, 128 slots each
    __syncthreads();

    // x_0 into hbuf[0][100..103] (published by the SYNC_LDS below)
    if (t == 0) {
        uint2 u;
        u.x = __builtin_bit_cast(unsigned, packh2(x[0], x[1]));
        u.y = __builtin_bit_cast(unsigned, packh2(x[2], 1.0f));
        *(uint2*)&hbuf[0][100] = u;
    }

    // ---- encoder weights ----
    // MFMA A-fragments, k in [0,64): wA[tile][ktile]; lane holds W[R=16Tg+col][32kt+8lg+j]
    f16x8 wA[4][2];
    #pragma unroll
    for (int tt = 0; tt < 4; ++tt) {
        #pragma unroll
        for (int kt = 0; kt < 2; ++kt) {
            f16x8 a;
            #pragma unroll
            for (int j = 0; j < 8; ++j) {
                float v = 0.0f;
                const int cellA = 4*(4*w + tt) + rep;
                if (alive && cellA < HID) {
                    const int k = 32*kt + 8*lg + j;           // < 64: Whh only
                    v = eWhh[(T*HID + cellA)*HID + k];
                }
                a[j] = (_Float16)v;
            }
            wA[tt][kt] = a;
        }
    }
    // VALU slice weights, k in [64+10rep, 74+10rep): wf[gate][5 pairs]
    const int cellV = 4*(4*w + T) + lg;     // this lane's owned cell
    const bool liveV = alive && (cellV < HID);
    float wf[4][5];
    #pragma unroll
    for (int g = 0; g < 4; ++g) {
        #pragma unroll
        for (int j = 0; j < 5; ++j) {
            float v0 = 0.0f, v1 = 0.0f;
            if (liveV) {
                const int wr = g*HID + cellV;
                const int k0 = 64 + 10*rep + 2*j, k1 = k0 + 1;
                v0 = (k0 < HID) ? eWhh[wr*HID + k0]
                   : (k0 < 103) ? eWih[wr*3 + (k0 - 100)] : (ebih[wr] + ebhh[wr]);
                v1 = (k1 < HID) ? eWhh[wr*HID + k1]
                   : (k1 < 103) ? eWih[wr*3 + (k1 - 100)] : (ebih[wr] + ebhh[wr]);
            }
            wf[g][j] = packh2(v0, v1);
        }
    }
    SYNC_LDS();

    const bool wrt = liveV && (rep == 0);   // unique writer per live cell
    const bool t1 = (T == 1), t2 = (T == 2), t3 = (T == 3);
    const f32x4 ZZ = {0.0f, 0.0f, 0.0f, 0.0f};
    float c = 0.0f;
    int p = 0;

    // ================ encoder: 4096 steps ================
    for (int s = 0; s < TENC; ++s) {
        if (alive) {
            const f16x8* hb = (const f16x8*)hbuf[p];
            const f16x8 B0 = hb[0 + lg];                  // k  0..31
            const f16x8 B1 = hb[4 + lg];                  // k 32..63
            const float* hfl = (const float*)hbuf[p];
            float hp[5];
            #pragma unroll
            for (int j = 0; j < 5; ++j) hp[j] = hfl[32 + 5*rep + j];   // k 64+10rep ..

            if (t == 0 && s + 1 < TENC)                   // prefetch x_{s+1}
                *(uint2*)&hbuf[p ^ 1][100] = xst[s + 1];

            // matrix pipe: k<64 for all 4 tiles
            f32x4 acc0 = __builtin_amdgcn_mfma_f32_16x16x32_f16(wA[0][0], B0, ZZ, 0, 0, 0);
            f32x4 acc1 = __builtin_amdgcn_mfma_f32_16x16x32_f16(wA[1][0], B0, ZZ, 0, 0, 0);
            f32x4 acc2 = __builtin_amdgcn_mfma_f32_16x16x32_f16(wA[2][0], B0, ZZ, 0, 0, 0);
            f32x4 acc3 = __builtin_amdgcn_mfma_f32_16x16x32_f16(wA[3][0], B0, ZZ, 0, 0, 0);
            acc0 = __builtin_amdgcn_mfma_f32_16x16x32_f16(wA[0][1], B1, acc0, 0, 0, 0);
            acc1 = __builtin_amdgcn_mfma_f32_16x16x32_f16(wA[1][1], B1, acc1, 0, 0, 0);
            acc2 = __builtin_amdgcn_mfma_f32_16x16x32_f16(wA[2][1], B1, acc2, 0, 0, 0);
            acc3 = __builtin_amdgcn_mfma_f32_16x16x32_f16(wA[3][1], B1, acc3, 0, 0, 0);

            // vector pipe (overlaps MFMA): k-slice dots
            float p0 = 0.0f, p1 = 0.0f, p2 = 0.0f, p3 = 0.0f;
            #pragma unroll
            for (int j = 0; j < 5; ++j) {
                p0 = fd2(wf[0][j], hp[j], p0);
                p1 = fd2(wf[1][j], hp[j], p1);
                p2 = fd2(wf[2][j], hp[j], p2);
                p3 = fd2(wf[3][j], hp[j], p3);
            }
            p0 = rsum4(p0); p1 = rsum4(p1); p2 = rsum4(p2); p3 = rsum4(p3);

            // select this lane's tile quad (static 4-way)
            f32x4 q = acc0;
            if (t1) q = acc1;
            if (t2) q = acc2;
            if (t3) q = acc3;

            const float a0 = q[0] + p0, a1 = q[1] + p1, a2 = q[2] + p2, a3 = q[3] + p3;
            const float fi = sigm(a0), ff = sigm(a1), fg = tanh_(a2), fo = sigm(a3);
            c = ff * c + fi * fg;                // replicated across the 4 rep lanes
            const float hn = fo * tanh_(c);
            if (wrt)
                hbuf[p ^ 1][cellV] = (_Float16)hn;
        }
        SYNC_LDS();
        p ^= 1;
    }

    // ================ transition: decoder input slot {yf0, 1, 0, 0} ================
    if (t == 0) {
        uint2 v;
        v.x = (yst[0] & 0xFFFFu) | 0x3C000000u;   // {yf0, f16(1.0)}
        v.y = 0u;
        *(uint2*)&hbuf[p][100] = v;
    }

    // ---- decoder weights (reuse wA/wf) ----
    #pragma unroll
    for (int tt = 0; tt < 4; ++tt) {
        #pragma unroll
        for (int kt = 0; kt < 2; ++kt) {
            f16x8 a;
            #pragma unroll
            for (int j = 0; j < 8; ++j) {
                float v = 0.0f;
                const int cellA = 4*(4*w + tt) + rep;
                if (alive && cellA < HID) {
                    const int k = 32*kt + 8*lg + j;
                    v = dWhh[(T*HID + cellA)*HID + k];
                }
                a[j] = (_Float16)v;
            }
            wA[tt][kt] = a;
        }
    }
    #pragma unroll
    for (int g = 0; g < 4; ++g) {
        #pragma unroll
        for (int j = 0; j < 5; ++j) {
            float v0 = 0.0f, v1 = 0.0f;
            if (liveV) {
                const int wr = g*HID + cellV;
                const int k0 = 64 + 10*rep + 2*j, k1 = k0 + 1;
                v0 = (k0 < HID) ? dWhh[wr*HID + k0]
                   : (k0 == 100) ? dWih[wr]
                   : (k0 == 101) ? (dbih[wr] + dbhh[wr]) : 0.0f;
                v1 = (k1 < HID) ? dWhh[wr*HID + k1]
                   : (k1 == 100) ? dWih[wr]
                   : (k1 == 101) ? (dbih[wr] + dbhh[wr]) : 0.0f;
            }
            wf[g][j] = packh2(v0, v1);
        }
    }
    SYNC_LDS();

    // ================ decoder: 4095 steps (ratio==1 -> teacher-forced) ================
    for (int s = 0; s < TDEC - 1; ++s) {
        if (alive) {
            const f16x8* hb = (const f16x8*)hbuf[p];
            const f16x8 B0 = hb[0 + lg];
            const f16x8 B1 = hb[4 + lg];
            const float* hfl = (const float*)hbuf[p];
            float hp[5];
            #pragma unroll
            for (int j = 0; j < 5; ++j) hp[j] = hfl[32 + 5*rep + j];

            if (t == 0 && s + 1 < TDEC - 1) {
                uint2 v;
                v.x = (yst[s + 1] & 0xFFFFu) | 0x3C000000u;
                v.y = 0u;
                *(uint2*)&hbuf[p ^ 1][100] = v;
            }

            f32x4 acc0 = __builtin_amdgcn_mfma_f32_16x16x32_f16(wA[0][0], B0, ZZ, 0, 0, 0);
            f32x4 acc1 = __builtin_amdgcn_mfma_f32_16x16x32_f16(wA[1][0], B0, ZZ, 0, 0, 0);
            f32x4 acc2 = __builtin_amdgcn_mfma_f32_16x16x32_f16(wA[2][0], B0, ZZ, 0, 0, 0);
            f32x4 acc3 = __builtin_amdgcn_mfma_f32_16x16x32_f16(wA[3][0], B0, ZZ, 0, 0, 0);
            acc0 = __builtin_amdgcn_mfma_f32_16x16x32_f16(wA[0][1], B1, acc0, 0, 0, 0);
            acc1 = __builtin_amdgcn_mfma_f32_16x16x32_f16(wA[1][1], B1, acc1, 0, 0, 0);
            acc2 = __builtin_amdgcn_mfma_f32_16x16x32_f16(wA[2][1], B1, acc2, 0, 0, 0);
            acc3 = __builtin_amdgcn_mfma_f32_16x16x32_f16(wA[3][1], B1, acc3, 0, 0, 0);

            float p0 = 0.0f, p1 = 0.0f, p2 = 0.0f, p3 = 0.0f;
            #pragma unroll
            for (int j = 0; j < 5; ++j) {
                p0 = fd2(wf[0][j], hp[j], p0);
                p1 = fd2(wf[1][j], hp[j], p1);
                p2 = fd2(wf[2][j], hp[j], p2);
                p3 = fd2(wf[3][j], hp[j], p3);
            }
            p0 = rsum4(p0); p1 = rsum4(p1); p2 = rsum4(p2); p3 = rsum4(p3);

            f32x4 q = acc0;
            if (t1) q = acc1;
            if (t2) q = acc2;
            if (t3) q = acc3;

            const float a0 = q[0] + p0, a1 = q[1] + p1, a2 = q[2] + p2, a3 = q[3] + p3;
            const float fi = sigm(a0), ff = sigm(a1), fg = tanh_(a2), fo = sigm(a3);
            c = ff * c + fi * fg;
            const float hn = fo * tanh_(c);
            if (wrt) {
                hbuf[p ^ 1][cellV] = (_Float16)hn;
                hsto[s * HID + cellV] = hn;      // global store, never fenced in-loop
            }
        }
        SYNC_LDS();
        p ^= 1;
    }
    // kernel end-of-dispatch drains the hsto stores before logits_k launches
}

// Parallel logits: out[t][r] = linW[r] . h_t + linb[r], last row zeroed.
__global__ __launch_bounds__(256)
void logits_k(const float* __restrict__ hsto, const float* __restrict__ linW,
              const float* __restrict__ linb, float* __restrict__ out)
{
    const int idx = blockIdx.x * 256 + threadIdx.x;
    if (idx >= TDEC * NCLS) return;
    const int tt = idx / NCLS;
    const int r  = idx % NCLS;
    if (tt >= TDEC - 1) { out[idx] = 0.0f; return; }
    const float* h  = hsto + tt * HID;
    const float* wr = linW + r * HID;
    float a = linb[r];
    #pragma unroll 4
    for (int k = 0; k < HID; ++k) a += wr[k] * h[k];
    out[idx] = a;
}

extern "C" void kernel_launch(void* const* d_in, const int* in_sizes, int n_in,
                              void* d_out, int out_size, void* d_ws, size_t ws_size,
                              hipStream_t stream)
{
    const float* x    = (const float*)d_in[0];
    const int*   y    = (const int*)  d_in[1];
    const float* eWih = (const float*)d_in[2];
    const float* eWhh = (const float*)d_in[3];
    const float* ebih = (const float*)d_in[4];
    const float* ebhh = (const float*)d_in[5];
    const float* dWih = (const float*)d_in[6];
    const float* dWhh = (const float*)d_in[7];
    const float* dbih = (const float*)d_in[8];
    const float* dbhh = (const float*)d_in[9];
    const float* linW = (const float*)d_in[10];
    const float* linb = (const float*)d_in[11];
    float* out  = (float*)d_out;
    float* hsto = (float*)d_ws;   // (TDEC-1)*HID*4 = 1.64 MB scratch

    lstm_rec<<<dim3(1), dim3(NTHR), 0, stream>>>(
        x, y, eWih, eWhh, ebih, ebhh, dWih, dWhh, dbih, dbhh, hsto);

    const int nout = TDEC * NCLS;
    logits_k<<<dim3((nout + 255) / 256), dim3(256), 0, stream>>>(hsto, linW, linb, out);
}